// Round 3
// baseline (419.595 us; speedup 1.0000x reference)
//
#include <hip/hip_runtime.h>
#include <hip/hip_bf16.h>
#include <cstdint>
#include <cstddef>

#define B_ 64
#define H_ 1024
#define V_ 32000
#define S_ 128

// ---- workspace layout (float offsets) ----
#define WS_GATES   0            // 2*64*4096 gate partials (K-split 2)
#define WS_SCORE   524288       // 8*64*128  attn score partials
#define WS_HATTP   589824       // 4*64*1024 h_att partials (K-split 4)
#define WS_Y       851968       // 64*32000  logits
#define WS_BF      2899968      // bf16 arrays (ushort), 655360 ushorts
// total 3,227,648 floats = 12.9 MB

// ---- output layout (pred, h_new, c_new concatenated) ----
#define OUT_H      2048000
#define OUT_C      2113536

typedef __attribute__((ext_vector_type(8))) short bf16x8;
typedef __attribute__((ext_vector_type(4))) float f32x4;

// truncation hi/lo bf16 split: x ~= hi + lo, |err| <~ 2^-16 |x|
__device__ __forceinline__ void bsplit(float x, unsigned short& hi, unsigned short& lo) {
  const unsigned int xb = __float_as_uint(x);
  hi = (unsigned short)(xb >> 16);
  const float r = x - __uint_as_float(xb & 0xFFFF0000u);
  lo = (unsigned short)(__float_as_uint(r) >> 16);
}

// =====================================================================
// Prep: gather emb[prev] and h0, split both to bf16 hi/lo. 64 x 256.
// =====================================================================
__global__ __launch_bounds__(256) void prep_split(
    const int* __restrict__ prev, const float* __restrict__ emb,
    const float* __restrict__ h0,
    unsigned short* __restrict__ xhi, unsigned short* __restrict__ xlo,
    unsigned short* __restrict__ hhi, unsigned short* __restrict__ hlo)
{
  const int b = blockIdx.x;
  const int k4 = threadIdx.x * 4;
  const float4 xv = *reinterpret_cast<const float4*>(emb + (size_t)prev[b] * H_ + k4);
  const float4 hv = *reinterpret_cast<const float4*>(h0 + (size_t)b * H_ + k4);
  ushort4 a, c, d, e;
  bsplit(xv.x, a.x, c.x); bsplit(xv.y, a.y, c.y);
  bsplit(xv.z, a.z, c.z); bsplit(xv.w, a.w, c.w);
  bsplit(hv.x, d.x, e.x); bsplit(hv.y, d.y, e.y);
  bsplit(hv.z, d.z, e.z); bsplit(hv.w, d.w, e.w);
  const size_t o = (size_t)b * H_ + k4;
  *reinterpret_cast<ushort4*>(xhi + o) = a;
  *reinterpret_cast<ushort4*>(xlo + o) = c;
  *reinterpret_cast<ushort4*>(hhi + o) = d;
  *reinterpret_cast<ushort4*>(hlo + o) = e;
}

// =====================================================================
// Gates GEMM via MFMA split-bf16:
//   part[0] = x @ W_ih^T ; part[1] = h0 @ W_hh^T   (each [64][4096], K=1024)
// grid (128, 2), block 128 = 2 waves; wave owns 16 n cols, all 64 m rows.
// W fp32 split in-register; 3 MFMA terms (hi*hi + lo*hi + hi*lo).
// =====================================================================
__global__ __launch_bounds__(128) void gates_mfma(
    const unsigned short* __restrict__ xhi, const unsigned short* __restrict__ xlo,
    const unsigned short* __restrict__ hhi, const unsigned short* __restrict__ hlo,
    const float* __restrict__ W_ih, const float* __restrict__ W_hh,
    float* __restrict__ gates_part)
{
  const int tid = threadIdx.x;
  const int wave = tid >> 6, lane = tid & 63;
  const int l15 = lane & 15, lk = lane >> 4;
  const int ks = blockIdx.y;
  const int n = blockIdx.x * 32 + wave * 16 + l15;
  const float* W = ks ? W_hh : W_ih;
  const unsigned short* Ah = ks ? hhi : xhi;
  const unsigned short* Al = ks ? hlo : xlo;
  const float* wp = W + (size_t)n * H_ + lk * 8;
  const unsigned short* ah_base = Ah + l15 * H_ + lk * 8;
  const unsigned short* al_base = Al + l15 * H_ + lk * 8;

  f32x4 acc[4];
  #pragma unroll
  for (int mt = 0; mt < 4; ++mt) acc[mt] = (f32x4){0.f, 0.f, 0.f, 0.f};

  #pragma unroll 2
  for (int c = 0; c < 32; ++c) {
    const int k0 = c * 32;
    const float4 wv0 = *reinterpret_cast<const float4*>(wp + k0);
    const float4 wv1 = *reinterpret_cast<const float4*>(wp + k0 + 4);
    const float wf[8] = {wv0.x, wv0.y, wv0.z, wv0.w, wv1.x, wv1.y, wv1.z, wv1.w};
    bf16x8 whi, wlo;
    #pragma unroll
    for (int e = 0; e < 8; ++e) {
      const unsigned int xb = __float_as_uint(wf[e]);
      whi[e] = (short)(xb >> 16);
      const float lof = wf[e] - __uint_as_float(xb & 0xFFFF0000u);
      wlo[e] = (short)(__float_as_uint(lof) >> 16);
    }
    #pragma unroll
    for (int mt = 0; mt < 4; ++mt) {
      const bf16x8 ah = *reinterpret_cast<const bf16x8*>(ah_base + (size_t)mt * 16 * H_ + k0);
      const bf16x8 al = *reinterpret_cast<const bf16x8*>(al_base + (size_t)mt * 16 * H_ + k0);
      acc[mt] = __builtin_amdgcn_mfma_f32_16x16x32_bf16(ah, whi, acc[mt], 0, 0, 0);
      acc[mt] = __builtin_amdgcn_mfma_f32_16x16x32_bf16(al, whi, acc[mt], 0, 0, 0);
      acc[mt] = __builtin_amdgcn_mfma_f32_16x16x32_bf16(ah, wlo, acc[mt], 0, 0, 0);
    }
  }
  #pragma unroll
  for (int mt = 0; mt < 4; ++mt)
    #pragma unroll
    for (int r = 0; r < 4; ++r)
      gates_part[((size_t)ks * 64 + mt * 16 + lk * 4 + r) * 4096 + n] = acc[mt][r];
}

// =====================================================================
// LSTM elementwise (2 gate partials + biases) fused with partial attn
// scores. grid 512 = (b<<3)|hc, block 128. Also emits h_new bf16 split.
// =====================================================================
__global__ __launch_bounds__(128) void lstm_scores(
    const float* __restrict__ gates_part,
    const float* __restrict__ b_ih, const float* __restrict__ b_hh,
    const float* __restrict__ c0, const float* __restrict__ enc,
    float* __restrict__ out_h, float* __restrict__ out_c,
    unsigned short* __restrict__ hnhi, unsigned short* __restrict__ hnlo,
    float* __restrict__ score_part)
{
  __shared__ float hs[128];
  const int b = blockIdx.x >> 3, hc = blockIdx.x & 7;
  const int tid = threadIdx.x;
  const int h = hc * 128 + tid;

  float gi = b_ih[h]        + b_hh[h];
  float gf = b_ih[1024 + h] + b_hh[1024 + h];
  float gg = b_ih[2048 + h] + b_hh[2048 + h];
  float go = b_ih[3072 + h] + b_hh[3072 + h];
  #pragma unroll
  for (int ks = 0; ks < 2; ++ks) {
    const float* g = gates_part + ((size_t)ks * 64 + b) * 4096;
    gi += g[h]; gf += g[1024 + h]; gg += g[2048 + h]; go += g[3072 + h];
  }
  const float si = 1.f / (1.f + expf(-gi));
  const float sf = 1.f / (1.f + expf(-gf));
  const float so = 1.f / (1.f + expf(-go));
  const float cn = sf * c0[b * H_ + h] + si * tanhf(gg);
  const float hn = so * tanhf(cn);
  out_c[b * H_ + h] = cn;
  out_h[b * H_ + h] = hn;
  unsigned short hi_, lo_;
  bsplit(hn, hi_, lo_);
  hnhi[b * H_ + h] = hi_;
  hnlo[b * H_ + h] = lo_;
  hs[tid] = hn;
  __syncthreads();

  const float* e = enc + ((size_t)b * H_ + hc * 128) * S_ + tid;
  float acc = 0.f;
  #pragma unroll 8
  for (int j = 0; j < 128; ++j) acc += hs[j] * e[(size_t)j * S_];
  score_part[((size_t)hc * 64 + b) * S_ + tid] = acc;
}

// =====================================================================
// Softmax over S fused with COALESCED context gather.
// grid 512 = (b<<3)|hg, block 256 (4 waves, 32 h rows each).
// Wave reads 2 consecutive enc rows per float4 load (1KB contiguous);
// alpha lives in registers; 32-lane shfl reduce per row.
// =====================================================================
__global__ __launch_bounds__(256) void attn_ctx(
    const float* __restrict__ score_part, const float* __restrict__ enc,
    unsigned short* __restrict__ thi, unsigned short* __restrict__ tlo)
{
  __shared__ __align__(16) float al[128];
  __shared__ float red[4];
  const int b = blockIdx.x >> 3, hg = blockIdx.x & 7;
  const int tid = threadIdx.x;

  float sc = 0.f;
  if (tid < 128) {
    #pragma unroll
    for (int ks = 0; ks < 8; ++ks) sc += score_part[((size_t)ks * 64 + b) * S_ + tid];
  }
  float v = (tid < 128) ? sc : -3.4e38f;
  #pragma unroll
  for (int off = 32; off; off >>= 1) v = fmaxf(v, __shfl_xor(v, off));
  if (tid == 0)  red[0] = v;
  if (tid == 64) red[1] = v;
  __syncthreads();
  const float mx = fmaxf(red[0], red[1]);
  const float ex = (tid < 128) ? expf(sc - mx) : 0.f;
  float sv = ex;
  #pragma unroll
  for (int off = 32; off; off >>= 1) sv += __shfl_xor(sv, off);
  if (tid == 0)  red[2] = sv;
  if (tid == 64) red[3] = sv;
  __syncthreads();
  const float inv = 1.f / (red[2] + red[3]);
  if (tid < 128) al[tid] = ex * inv;
  __syncthreads();

  const int wave = tid >> 6, lane = tid & 63;
  const int hoff = lane >> 5, s4 = (lane & 31) * 4;
  const float4 av = *reinterpret_cast<const float4*>(&al[s4]);
  const int hbase = hg * 128 + wave * 32;
  #pragma unroll 4
  for (int r = 0; r < 16; ++r) {
    const int h = hbase + r * 2 + hoff;
    const float4 ev = *reinterpret_cast<const float4*>(enc + ((size_t)b * H_ + h) * S_ + s4);
    float acc = ev.x * av.x + ev.y * av.y + ev.z * av.z + ev.w * av.w;
    #pragma unroll
    for (int off = 16; off; off >>= 1) acc += __shfl_xor(acc, off);
    if ((lane & 31) == 0) {
      unsigned short hi_, lo_;
      bsplit(acc, hi_, lo_);
      thi[b * H_ + h] = hi_;
      tlo[b * H_ + h] = lo_;
    }
  }
}

// =====================================================================
// h_att GEMM via MFMA split-bf16 (K-split 4):
//   ks 0,1: h_new @ W1^T (K halves); ks 2,3: t @ W2^T (K halves)
// grid (32, 4), block 128.
// =====================================================================
__global__ __launch_bounds__(128) void hatt_mfma(
    const unsigned short* __restrict__ hnhi, const unsigned short* __restrict__ hnlo,
    const unsigned short* __restrict__ thi, const unsigned short* __restrict__ tlo,
    const float* __restrict__ W1, const float* __restrict__ W2,
    float* __restrict__ hatt_part)
{
  const int tid = threadIdx.x;
  const int wave = tid >> 6, lane = tid & 63;
  const int l15 = lane & 15, lk = lane >> 4;
  const int ks = blockIdx.y;
  const int n = blockIdx.x * 32 + wave * 16 + l15;
  const int koff = (ks & 1) * 512;
  const float* W = (ks < 2) ? W1 : W2;
  const unsigned short* Ah = (ks < 2) ? hnhi : thi;
  const unsigned short* Al = (ks < 2) ? hnlo : tlo;
  const float* wp = W + (size_t)n * H_ + koff + lk * 8;
  const unsigned short* ah_base = Ah + l15 * H_ + koff + lk * 8;
  const unsigned short* al_base = Al + l15 * H_ + koff + lk * 8;

  f32x4 acc[4];
  #pragma unroll
  for (int mt = 0; mt < 4; ++mt) acc[mt] = (f32x4){0.f, 0.f, 0.f, 0.f};

  #pragma unroll 2
  for (int c = 0; c < 16; ++c) {
    const int k0 = c * 32;
    const float4 wv0 = *reinterpret_cast<const float4*>(wp + k0);
    const float4 wv1 = *reinterpret_cast<const float4*>(wp + k0 + 4);
    const float wf[8] = {wv0.x, wv0.y, wv0.z, wv0.w, wv1.x, wv1.y, wv1.z, wv1.w};
    bf16x8 whi, wlo;
    #pragma unroll
    for (int e = 0; e < 8; ++e) {
      const unsigned int xb = __float_as_uint(wf[e]);
      whi[e] = (short)(xb >> 16);
      const float lof = wf[e] - __uint_as_float(xb & 0xFFFF0000u);
      wlo[e] = (short)(__float_as_uint(lof) >> 16);
    }
    #pragma unroll
    for (int mt = 0; mt < 4; ++mt) {
      const bf16x8 ah = *reinterpret_cast<const bf16x8*>(ah_base + (size_t)mt * 16 * H_ + k0);
      const bf16x8 al = *reinterpret_cast<const bf16x8*>(al_base + (size_t)mt * 16 * H_ + k0);
      acc[mt] = __builtin_amdgcn_mfma_f32_16x16x32_bf16(ah, whi, acc[mt], 0, 0, 0);
      acc[mt] = __builtin_amdgcn_mfma_f32_16x16x32_bf16(al, whi, acc[mt], 0, 0, 0);
      acc[mt] = __builtin_amdgcn_mfma_f32_16x16x32_bf16(ah, wlo, acc[mt], 0, 0, 0);
    }
  }
  #pragma unroll
  for (int mt = 0; mt < 4; ++mt)
    #pragma unroll
    for (int r = 0; r < 4; ++r)
      hatt_part[((size_t)ks * 64 + mt * 16 + lk * 4 + r) * 1024 + n] = acc[mt][r];
}

// =====================================================================
// h_att epilogue: sum 4 partials + biases, tanh, bf16 hi/lo split. 256x256.
// =====================================================================
__global__ __launch_bounds__(256) void hatt_ep(
    const float* __restrict__ hatt_part,
    const float* __restrict__ b1, const float* __restrict__ b2,
    unsigned short* __restrict__ Ahi, unsigned short* __restrict__ Alo)
{
  const int i = blockIdx.x * 256 + threadIdx.x;   // 65536
  const int col = i & (H_ - 1);
  float a = b1[col] + b2[col];
  #pragma unroll
  for (int ks = 0; ks < 4; ++ks) a += hatt_part[(size_t)ks * 65536 + i];
  const float t = tanhf(a);
  unsigned short hi_, lo_;
  bsplit(t, hi_, lo_);
  Ahi[i] = hi_;
  Alo[i] = lo_;
}

// =====================================================================
// Logits GEMM via MFMA split-bf16: y = h_att @ W_w^T + W_b.
// grid 500, block 256 = 4 waves; wave owns 16 n cols, all 64 m rows.
// =====================================================================
__global__ __launch_bounds__(256, 2) void gemm_big_mfma(
    const unsigned short* __restrict__ Ahi, const unsigned short* __restrict__ Alo,
    const float* __restrict__ W, const float* __restrict__ bias,
    float* __restrict__ y)
{
  const int tid = threadIdx.x;
  const int wave = tid >> 6, lane = tid & 63;
  const int l15 = lane & 15, lk = lane >> 4;
  const int n = blockIdx.x * 64 + wave * 16 + l15;
  const float* wp = W + (size_t)n * H_ + lk * 8;
  const unsigned short* ah_base = Ahi + l15 * H_ + lk * 8;
  const unsigned short* al_base = Alo + l15 * H_ + lk * 8;

  f32x4 acc[4];
  #pragma unroll
  for (int mt = 0; mt < 4; ++mt) acc[mt] = (f32x4){0.f, 0.f, 0.f, 0.f};

  #pragma unroll 4
  for (int ks = 0; ks < 32; ++ks) {
    const int k0 = ks * 32;
    const float4 wv0 = *reinterpret_cast<const float4*>(wp + k0);
    const float4 wv1 = *reinterpret_cast<const float4*>(wp + k0 + 4);
    const float wf[8] = {wv0.x, wv0.y, wv0.z, wv0.w, wv1.x, wv1.y, wv1.z, wv1.w};
    bf16x8 whi, wlo;
    #pragma unroll
    for (int e = 0; e < 8; ++e) {
      const unsigned int xb = __float_as_uint(wf[e]);
      whi[e] = (short)(xb >> 16);
      const float lof = wf[e] - __uint_as_float(xb & 0xFFFF0000u);
      wlo[e] = (short)(__float_as_uint(lof) >> 16);
    }
    #pragma unroll
    for (int mt = 0; mt < 4; ++mt) {
      const bf16x8 ah = *reinterpret_cast<const bf16x8*>(ah_base + (size_t)mt * 16 * H_ + k0);
      const bf16x8 al = *reinterpret_cast<const bf16x8*>(al_base + (size_t)mt * 16 * H_ + k0);
      acc[mt] = __builtin_amdgcn_mfma_f32_16x16x32_bf16(ah, whi, acc[mt], 0, 0, 0);
      acc[mt] = __builtin_amdgcn_mfma_f32_16x16x32_bf16(al, whi, acc[mt], 0, 0, 0);
      acc[mt] = __builtin_amdgcn_mfma_f32_16x16x32_bf16(ah, wlo, acc[mt], 0, 0, 0);
    }
  }
  const float bn = bias[n];
  #pragma unroll
  for (int mt = 0; mt < 4; ++mt)
    #pragma unroll
    for (int r = 0; r < 4; ++r)
      y[(size_t)(mt * 16 + lk * 4 + r) * V_ + n] = acc[mt][r] + bn;
}

// =====================================================================
// log-softmax: 3 passes over one row (row L2-resident after pass 1).
// =====================================================================
__global__ __launch_bounds__(1024) void lse_pred(
    const float* __restrict__ y, float* __restrict__ pred)
{
  __shared__ float red[16];
  __shared__ float bc;
  const int b = blockIdx.x, tid = threadIdx.x;
  const float* yr = y + (size_t)b * V_;

  float m = -3.4e38f;
  for (int i = tid; i < V_; i += 1024) m = fmaxf(m, yr[i]);
  #pragma unroll
  for (int off = 32; off; off >>= 1) m = fmaxf(m, __shfl_xor(m, off));
  if ((tid & 63) == 0) red[tid >> 6] = m;
  __syncthreads();
  if (tid == 0) {
    float mx = red[0];
    #pragma unroll
    for (int w = 1; w < 16; ++w) mx = fmaxf(mx, red[w]);
    bc = mx;
  }
  __syncthreads();
  const float mx = bc;
  float s = 0.f;
  for (int i = tid; i < V_; i += 1024) s += expf(yr[i] - mx);
  #pragma unroll
  for (int off = 32; off; off >>= 1) s += __shfl_xor(s, off);
  if ((tid & 63) == 0) red[tid >> 6] = s;
  __syncthreads();
  if (tid == 0) {
    float tot = 0.f;
    #pragma unroll
    for (int w = 0; w < 16; ++w) tot += red[w];
    bc = mx + logf(tot);
  }
  __syncthreads();
  const float lse = bc;
  float* pr = pred + (size_t)b * V_;
  for (int i = tid; i < V_; i += 1024) pr[i] = yr[i] - lse;
}

// =====================================================================
extern "C" void kernel_launch(void* const* d_in, const int* in_sizes, int n_in,
                              void* d_out, int out_size, void* d_ws, size_t ws_size,
                              hipStream_t stream)
{
  const int*   prev = (const int*)  d_in[0];
  const float* h0   = (const float*)d_in[1];
  const float* c0   = (const float*)d_in[2];
  const float* enc  = (const float*)d_in[3];
  const float* emb  = (const float*)d_in[4];
  const float* W_ih = (const float*)d_in[5];
  const float* W_hh = (const float*)d_in[6];
  const float* b_ih = (const float*)d_in[7];
  const float* b_hh = (const float*)d_in[8];
  const float* W1_w = (const float*)d_in[9];
  const float* W1_b = (const float*)d_in[10];
  const float* W2_w = (const float*)d_in[11];
  const float* W2_b = (const float*)d_in[12];
  const float* W_w  = (const float*)d_in[13];
  const float* W_b  = (const float*)d_in[14];

  float* outp  = (float*)d_out;
  float* pred  = outp;
  float* h_new = outp + OUT_H;
  float* c_new = outp + OUT_C;

  float* ws         = (float*)d_ws;
  float* gates_part = ws + WS_GATES;
  float* score_part = ws + WS_SCORE;
  float* hatt_part  = ws + WS_HATTP;
  float* y          = ws + WS_Y;
  unsigned short* us = (unsigned short*)(ws + WS_BF);
  unsigned short* xhi  = us;
  unsigned short* xlo  = us + 65536;
  unsigned short* h0hi = us + 131072;
  unsigned short* h0lo = us + 196608;
  unsigned short* hnhi = us + 262144;
  unsigned short* hnlo = us + 327680;
  unsigned short* thi  = us + 393216;
  unsigned short* tlo  = us + 458752;
  unsigned short* Ahi  = us + 524288;
  unsigned short* Alo  = us + 589824;

  // 1) gather + bf16-split x (=emb[prev]) and h0
  prep_split<<<64, 256, 0, stream>>>(prev, emb, h0, xhi, xlo, h0hi, h0lo);
  // 2) gate partials via MFMA: x@W_ih^T, h0@W_hh^T
  gates_mfma<<<dim3(128, 2), 128, 0, stream>>>(
      xhi, xlo, h0hi, h0lo, W_ih, W_hh, gates_part);
  // 3) LSTM elementwise + h_new split + partial attention scores
  lstm_scores<<<512, 128, 0, stream>>>(
      gates_part, b_ih, b_hh, c0, enc, h_new, c_new, hnhi, hnlo, score_part);
  // 4) softmax + coalesced context (writes t split)
  attn_ctx<<<512, 256, 0, stream>>>(score_part, enc, thi, tlo);
  // 5) h_att partials via MFMA: h_new@W1^T, t@W2^T (K-split 4)
  hatt_mfma<<<dim3(32, 4), 128, 0, stream>>>(
      hnhi, hnlo, thi, tlo, W1_w, W2_w, hatt_part);
  // 6) h_att epilogue (sum + biases + tanh + split)
  hatt_ep<<<256, 256, 0, stream>>>(hatt_part, W1_b, W2_b, Ahi, Alo);
  // 7) logits via MFMA split-bf16
  gemm_big_mfma<<<500, 256, 0, stream>>>(Ahi, Alo, W_w, W_b, y);
  // 8) log-softmax
  lse_pred<<<64, 1024, 0, stream>>>(y, pred);
}

// Round 4
// 399.434 us; speedup vs baseline: 1.0505x; 1.0505x over previous
//
#include <hip/hip_runtime.h>
#include <hip/hip_bf16.h>
#include <cstdint>
#include <cstddef>

#define B_ 64
#define H_ 1024
#define V_ 32000
#define S_ 128

// ---- workspace layout (float offsets) ----
#define WS_GATES   0            // 8*64*4096 gate partials (2 mat x 4 kseg)
#define WS_SCORE   2097152      // 16*64*128 attn score partials
#define WS_HATTP   2228224      // 8*64*1024 h_att partials
#define WS_YP      2752512      // 2*64*32000 logit partials (K-split 2)
#define WS_STATS   6848512      // 64*8*2 lse chunk stats
#define WS_BF      6849536      // bf16 arrays (ushort), 655360 ushorts
// total 7,177,216 floats = 28.7 MB

// ---- output layout (pred, h_new, c_new concatenated) ----
#define OUT_H      2048000
#define OUT_C      2113536

typedef __attribute__((ext_vector_type(8))) short bf16x8;
typedef __attribute__((ext_vector_type(4))) float f32x4;

// truncation hi/lo bf16 split: x ~= hi + lo, |err| <~ 2^-16 |x|
__device__ __forceinline__ void bsplit(float x, unsigned short& hi, unsigned short& lo) {
  const unsigned int xb = __float_as_uint(x);
  hi = (unsigned short)(xb >> 16);
  const float r = x - __uint_as_float(xb & 0xFFFF0000u);
  lo = (unsigned short)(__float_as_uint(r) >> 16);
}

// Shared MFMA panel: NITER k-steps of 32; W fp32 (split in-register, 3-term),
// A pre-split bf16 hi/lo. Rolling W prefetch (depth 1) + grouped A loads
// give ~10 loads in flight per wave per iteration.
template<int NITER>
__device__ __forceinline__ void mfma_panel(
    const float* __restrict__ wp,
    const unsigned short* __restrict__ ah_base,
    const unsigned short* __restrict__ al_base,
    f32x4 acc[4])
{
  float4 w0 = *reinterpret_cast<const float4*>(wp);
  float4 w1 = *reinterpret_cast<const float4*>(wp + 4);
  #pragma unroll
  for (int c = 0; c < NITER; ++c) {
    const int k0 = c * 32;
    float4 nw0, nw1;
    if (c + 1 < NITER) {   // prefetch next W chunk (in flight during compute)
      nw0 = *reinterpret_cast<const float4*>(wp + k0 + 32);
      nw1 = *reinterpret_cast<const float4*>(wp + k0 + 36);
    }
    bf16x8 ah[4], al[4];   // grouped A loads (one waitcnt before MFMA chain)
    #pragma unroll
    for (int mt = 0; mt < 4; ++mt) {
      ah[mt] = *reinterpret_cast<const bf16x8*>(ah_base + (size_t)mt * 16 * H_ + k0);
      al[mt] = *reinterpret_cast<const bf16x8*>(al_base + (size_t)mt * 16 * H_ + k0);
    }
    const float wf[8] = {w0.x, w0.y, w0.z, w0.w, w1.x, w1.y, w1.z, w1.w};
    bf16x8 whi, wlo;
    #pragma unroll
    for (int e = 0; e < 8; ++e) {
      const unsigned int xb = __float_as_uint(wf[e]);
      whi[e] = (short)(xb >> 16);
      const float lof = wf[e] - __uint_as_float(xb & 0xFFFF0000u);
      wlo[e] = (short)(__float_as_uint(lof) >> 16);
    }
    #pragma unroll
    for (int mt = 0; mt < 4; ++mt) {
      acc[mt] = __builtin_amdgcn_mfma_f32_16x16x32_bf16(ah[mt], whi, acc[mt], 0, 0, 0);
      acc[mt] = __builtin_amdgcn_mfma_f32_16x16x32_bf16(al[mt], whi, acc[mt], 0, 0, 0);
      acc[mt] = __builtin_amdgcn_mfma_f32_16x16x32_bf16(ah[mt], wlo, acc[mt], 0, 0, 0);
    }
    if (c + 1 < NITER) { w0 = nw0; w1 = nw1; }
  }
}

// =====================================================================
// Prep: gather emb[prev] and h0, split both to bf16 hi/lo. 64 x 256.
// =====================================================================
__global__ __launch_bounds__(256) void prep_split(
    const int* __restrict__ prev, const float* __restrict__ emb,
    const float* __restrict__ h0,
    unsigned short* __restrict__ xhi, unsigned short* __restrict__ xlo,
    unsigned short* __restrict__ hhi, unsigned short* __restrict__ hlo)
{
  const int b = blockIdx.x;
  const int k4 = threadIdx.x * 4;
  const float4 xv = *reinterpret_cast<const float4*>(emb + (size_t)prev[b] * H_ + k4);
  const float4 hv = *reinterpret_cast<const float4*>(h0 + (size_t)b * H_ + k4);
  ushort4 a, c, d, e;
  bsplit(xv.x, a.x, c.x); bsplit(xv.y, a.y, c.y);
  bsplit(xv.z, a.z, c.z); bsplit(xv.w, a.w, c.w);
  bsplit(hv.x, d.x, e.x); bsplit(hv.y, d.y, e.y);
  bsplit(hv.z, d.z, e.z); bsplit(hv.w, d.w, e.w);
  const size_t o = (size_t)b * H_ + k4;
  *reinterpret_cast<ushort4*>(xhi + o) = a;
  *reinterpret_cast<ushort4*>(xlo + o) = c;
  *reinterpret_cast<ushort4*>(hhi + o) = d;
  *reinterpret_cast<ushort4*>(hlo + o) = e;
}

// =====================================================================
// Gates GEMM: part[ks] with ks = mat*4+kseg; mat 0: x@W_ih^T, 1: h0@W_hh^T,
// kseg = 256-wide K slice. grid (64, 8), block 256 (4 waves x 16 n-cols).
// =====================================================================
__global__ __launch_bounds__(256, 4) void gates_mfma(
    const unsigned short* __restrict__ xhi, const unsigned short* __restrict__ xlo,
    const unsigned short* __restrict__ hhi, const unsigned short* __restrict__ hlo,
    const float* __restrict__ W_ih, const float* __restrict__ W_hh,
    float* __restrict__ gates_part)
{
  const int tid = threadIdx.x;
  const int wave = tid >> 6, lane = tid & 63;
  const int l15 = lane & 15, lk = lane >> 4;
  const int ks = blockIdx.y;
  const int mat = ks >> 2, koff = (ks & 3) * 256;
  const int n = blockIdx.x * 64 + wave * 16 + l15;
  const float* W = mat ? W_hh : W_ih;
  const unsigned short* Ah = mat ? hhi : xhi;
  const unsigned short* Al = mat ? hlo : xlo;

  f32x4 acc[4];
  #pragma unroll
  for (int mt = 0; mt < 4; ++mt) acc[mt] = (f32x4){0.f, 0.f, 0.f, 0.f};
  mfma_panel<8>(W + (size_t)n * H_ + koff + lk * 8,
                Ah + l15 * H_ + koff + lk * 8,
                Al + l15 * H_ + koff + lk * 8, acc);
  #pragma unroll
  for (int mt = 0; mt < 4; ++mt)
    #pragma unroll
    for (int r = 0; r < 4; ++r)
      gates_part[((size_t)ks * 64 + mt * 16 + lk * 4 + r) * 4096 + n] = acc[mt][r];
}

// =====================================================================
// LSTM elementwise: sum 8 gate partials + biases, gate math.
// grid 256 x 256 (i = b*1024 + h). Writes h_new/c_new + hn bf16 split.
// =====================================================================
__global__ __launch_bounds__(256) void k_lstm(
    const float* __restrict__ gates_part,
    const float* __restrict__ b_ih, const float* __restrict__ b_hh,
    const float* __restrict__ c0,
    float* __restrict__ out_h, float* __restrict__ out_c,
    unsigned short* __restrict__ hnhi, unsigned short* __restrict__ hnlo)
{
  const int i = blockIdx.x * 256 + threadIdx.x;   // 65536
  const int h = i & (H_ - 1);
  float gi = b_ih[h]        + b_hh[h];
  float gf = b_ih[1024 + h] + b_hh[1024 + h];
  float gg = b_ih[2048 + h] + b_hh[2048 + h];
  float go = b_ih[3072 + h] + b_hh[3072 + h];
  const int b = i >> 10;
  #pragma unroll
  for (int ks = 0; ks < 8; ++ks) {
    const float* g = gates_part + ((size_t)ks * 64 + b) * 4096;
    gi += g[h]; gf += g[1024 + h]; gg += g[2048 + h]; go += g[3072 + h];
  }
  const float si = 1.f / (1.f + expf(-gi));
  const float sf = 1.f / (1.f + expf(-gf));
  const float so = 1.f / (1.f + expf(-go));
  const float cn = sf * c0[i] + si * tanhf(gg);
  const float hn = so * tanhf(cn);
  out_c[i] = cn;
  out_h[i] = hn;
  unsigned short hi_, lo_;
  bsplit(hn, hi_, lo_);
  hnhi[i] = hi_;
  hnlo[i] = lo_;
}

// =====================================================================
// Attention score partials: score_part[hc][b][s] = sum over 64 h of chunk.
// grid 1024 = b*16+hc, block 128 (thread = s).
// =====================================================================
__global__ __launch_bounds__(128) void k_scores(
    const float* __restrict__ h_new, const float* __restrict__ enc,
    float* __restrict__ score_part)
{
  __shared__ float hs[64];
  const int b = blockIdx.x >> 4, hc = blockIdx.x & 15;
  const int tid = threadIdx.x;
  if (tid < 64) hs[tid] = h_new[b * H_ + hc * 64 + tid];
  __syncthreads();
  const float* e = enc + ((size_t)b * H_ + hc * 64) * S_ + tid;
  float acc = 0.f;
  #pragma unroll 8
  for (int j = 0; j < 64; ++j) acc += hs[j] * e[(size_t)j * S_];
  score_part[((size_t)hc * 64 + b) * S_ + tid] = acc;
}

// =====================================================================
// Softmax over S (sum 16 partials) fused with coalesced context gather.
// grid 512 = b*8+hg, block 256 (4 waves, 32 h rows each).
// =====================================================================
__global__ __launch_bounds__(256) void attn_ctx(
    const float* __restrict__ score_part, const float* __restrict__ enc,
    unsigned short* __restrict__ thi, unsigned short* __restrict__ tlo)
{
  __shared__ __align__(16) float al[128];
  __shared__ float red[4];
  const int b = blockIdx.x >> 3, hg = blockIdx.x & 7;
  const int tid = threadIdx.x;

  float sc = 0.f;
  if (tid < 128) {
    #pragma unroll
    for (int ks = 0; ks < 16; ++ks) sc += score_part[((size_t)ks * 64 + b) * S_ + tid];
  }
  float v = (tid < 128) ? sc : -3.4e38f;
  #pragma unroll
  for (int off = 32; off; off >>= 1) v = fmaxf(v, __shfl_xor(v, off));
  if (tid == 0)  red[0] = v;
  if (tid == 64) red[1] = v;
  __syncthreads();
  const float mx = fmaxf(red[0], red[1]);
  const float ex = (tid < 128) ? expf(sc - mx) : 0.f;
  float sv = ex;
  #pragma unroll
  for (int off = 32; off; off >>= 1) sv += __shfl_xor(sv, off);
  if (tid == 0)  red[2] = sv;
  if (tid == 64) red[3] = sv;
  __syncthreads();
  const float inv = 1.f / (red[2] + red[3]);
  if (tid < 128) al[tid] = ex * inv;
  __syncthreads();

  const int wave = tid >> 6, lane = tid & 63;
  const int hoff = lane >> 5, s4 = (lane & 31) * 4;
  const float4 av = *reinterpret_cast<const float4*>(&al[s4]);
  const int hbase = hg * 128 + wave * 32;
  #pragma unroll 8
  for (int r = 0; r < 16; ++r) {
    const int h = hbase + r * 2 + hoff;
    const float4 ev = *reinterpret_cast<const float4*>(enc + ((size_t)b * H_ + h) * S_ + s4);
    float acc = ev.x * av.x + ev.y * av.y + ev.z * av.z + ev.w * av.w;
    #pragma unroll
    for (int off = 16; off; off >>= 1) acc += __shfl_xor(acc, off);
    if ((lane & 31) == 0) {
      unsigned short hi_, lo_;
      bsplit(acc, hi_, lo_);
      thi[b * H_ + h] = hi_;
      tlo[b * H_ + h] = lo_;
    }
  }
}

// =====================================================================
// h_att GEMM: part[ks], ks = mat*4+kseg; mat 0: h_new@W1^T, 1: t@W2^T.
// grid (16, 8), block 256 (4 waves x 16 n-cols).
// =====================================================================
__global__ __launch_bounds__(256, 4) void hatt_mfma(
    const unsigned short* __restrict__ hnhi, const unsigned short* __restrict__ hnlo,
    const unsigned short* __restrict__ thi, const unsigned short* __restrict__ tlo,
    const float* __restrict__ W1, const float* __restrict__ W2,
    float* __restrict__ hatt_part)
{
  const int tid = threadIdx.x;
  const int wave = tid >> 6, lane = tid & 63;
  const int l15 = lane & 15, lk = lane >> 4;
  const int ks = blockIdx.y;
  const int mat = ks >> 2, koff = (ks & 3) * 256;
  const int n = blockIdx.x * 64 + wave * 16 + l15;
  const float* W = mat ? W2 : W1;
  const unsigned short* Ah = mat ? thi : hnhi;
  const unsigned short* Al = mat ? tlo : hnlo;

  f32x4 acc[4];
  #pragma unroll
  for (int mt = 0; mt < 4; ++mt) acc[mt] = (f32x4){0.f, 0.f, 0.f, 0.f};
  mfma_panel<8>(W + (size_t)n * H_ + koff + lk * 8,
                Ah + l15 * H_ + koff + lk * 8,
                Al + l15 * H_ + koff + lk * 8, acc);
  #pragma unroll
  for (int mt = 0; mt < 4; ++mt)
    #pragma unroll
    for (int r = 0; r < 4; ++r)
      hatt_part[((size_t)ks * 64 + mt * 16 + lk * 4 + r) * 1024 + n] = acc[mt][r];
}

// =====================================================================
// h_att epilogue: sum 8 partials + biases, tanh, bf16 hi/lo split. 256x256.
// =====================================================================
__global__ __launch_bounds__(256) void hatt_ep(
    const float* __restrict__ hatt_part,
    const float* __restrict__ b1, const float* __restrict__ b2,
    unsigned short* __restrict__ Ahi, unsigned short* __restrict__ Alo)
{
  const int i = blockIdx.x * 256 + threadIdx.x;   // 65536
  const int col = i & (H_ - 1);
  float a = b1[col] + b2[col];
  #pragma unroll
  for (int ks = 0; ks < 8; ++ks) a += hatt_part[(size_t)ks * 65536 + i];
  const float t = tanhf(a);
  unsigned short hi_, lo_;
  bsplit(t, hi_, lo_);
  Ahi[i] = hi_;
  Alo[i] = lo_;
}

// =====================================================================
// Logits GEMM (K-split 2): ypart[ks] = h_att[:, ks*512:+512] @ W^T slice.
// grid (500, 2), block 256 (4 waves x 16 n-cols). Bias folded into lse.
// =====================================================================
__global__ __launch_bounds__(256, 4) void gemm_big_mfma(
    const unsigned short* __restrict__ Ahi, const unsigned short* __restrict__ Alo,
    const float* __restrict__ W, float* __restrict__ ypart)
{
  const int tid = threadIdx.x;
  const int wave = tid >> 6, lane = tid & 63;
  const int l15 = lane & 15, lk = lane >> 4;
  const int ks = blockIdx.y, koff = ks * 512;
  const int n = blockIdx.x * 64 + wave * 16 + l15;

  f32x4 acc[4];
  #pragma unroll
  for (int mt = 0; mt < 4; ++mt) acc[mt] = (f32x4){0.f, 0.f, 0.f, 0.f};
  mfma_panel<16>(W + (size_t)n * H_ + koff + lk * 8,
                 Ahi + l15 * H_ + koff + lk * 8,
                 Alo + l15 * H_ + koff + lk * 8, acc);
  float* yp = ypart + (size_t)ks * 64 * V_;
  #pragma unroll
  for (int mt = 0; mt < 4; ++mt)
    #pragma unroll
    for (int r = 0; r < 4; ++r)
      yp[(size_t)(mt * 16 + lk * 4 + r) * V_ + n] = acc[mt][r];
}

// =====================================================================
// LSE pass 1: per (b, chunk of 4000): v = p0+p1+bias held in regs,
// chunk-local max + sumexp -> stats. grid 512 = b*8+ch, block 256.
// =====================================================================
__global__ __launch_bounds__(256) void lse1(
    const float* __restrict__ yp, const float* __restrict__ bias,
    float* __restrict__ stats)
{
  __shared__ float sm[4][2];
  const int b = blockIdx.x >> 3, ch = blockIdx.x & 7;
  const int tid = threadIdx.x;
  const float* p0 = yp + (size_t)b * V_ + ch * 4000;
  const float* p1 = p0 + (size_t)64 * V_;
  const float* bs = bias + ch * 4000;

  float v[16];
  float m = -3.4e38f;
  #pragma unroll
  for (int j = 0; j < 16; ++j) {
    const int c = tid + j * 256;
    if (c < 4000) {
      v[j] = p0[c] + p1[c] + bs[c];
      m = fmaxf(m, v[j]);
    }
  }
  float s = 0.f;
  #pragma unroll
  for (int j = 0; j < 16; ++j) {
    const int c = tid + j * 256;
    if (c < 4000) s += expf(v[j] - m);
  }
  #pragma unroll
  for (int off = 32; off; off >>= 1) {
    const float m2 = __shfl_xor(m, off);
    const float s2 = __shfl_xor(s, off);
    const float M = fmaxf(m, m2);
    s = s * expf(m - M) + s2 * expf(m2 - M);
    m = M;
  }
  if ((tid & 63) == 0) { sm[tid >> 6][0] = m; sm[tid >> 6][1] = s; }
  __syncthreads();
  if (tid == 0) {
    float M = fmaxf(fmaxf(sm[0][0], sm[1][0]), fmaxf(sm[2][0], sm[3][0]));
    float S = 0.f;
    #pragma unroll
    for (int w = 0; w < 4; ++w) S += sm[w][1] * expf(sm[w][0] - M);
    stats[(b * 8 + ch) * 2]     = M;
    stats[(b * 8 + ch) * 2 + 1] = S;
  }
}

// =====================================================================
// LSE pass 2: combine 8 chunk stats -> lse; recompute v, write pred.
// grid 512 = b*8+ch, block 256.
// =====================================================================
__global__ __launch_bounds__(256) void lse2(
    const float* __restrict__ yp, const float* __restrict__ bias,
    const float* __restrict__ stats, float* __restrict__ pred)
{
  const int b = blockIdx.x >> 3, ch = blockIdx.x & 7;
  const int tid = threadIdx.x;
  float M = -3.4e38f;
  #pragma unroll
  for (int i = 0; i < 8; ++i) M = fmaxf(M, stats[(b * 8 + i) * 2]);
  float S = 0.f;
  #pragma unroll
  for (int i = 0; i < 8; ++i)
    S += stats[(b * 8 + i) * 2 + 1] * expf(stats[(b * 8 + i) * 2] - M);
  const float lse = M + logf(S);

  const float* p0 = yp + (size_t)b * V_ + ch * 4000;
  const float* p1 = p0 + (size_t)64 * V_;
  const float* bs = bias + ch * 4000;
  float* pr = pred + (size_t)b * V_ + ch * 4000;
  #pragma unroll
  for (int j = 0; j < 16; ++j) {
    const int c = tid + j * 256;
    if (c < 4000) pr[c] = p0[c] + p1[c] + bs[c] - lse;
  }
}

// =====================================================================
extern "C" void kernel_launch(void* const* d_in, const int* in_sizes, int n_in,
                              void* d_out, int out_size, void* d_ws, size_t ws_size,
                              hipStream_t stream)
{
  const int*   prev = (const int*)  d_in[0];
  const float* h0   = (const float*)d_in[1];
  const float* c0   = (const float*)d_in[2];
  const float* enc  = (const float*)d_in[3];
  const float* emb  = (const float*)d_in[4];
  const float* W_ih = (const float*)d_in[5];
  const float* W_hh = (const float*)d_in[6];
  const float* b_ih = (const float*)d_in[7];
  const float* b_hh = (const float*)d_in[8];
  const float* W1_w = (const float*)d_in[9];
  const float* W1_b = (const float*)d_in[10];
  const float* W2_w = (const float*)d_in[11];
  const float* W2_b = (const float*)d_in[12];
  const float* W_w  = (const float*)d_in[13];
  const float* W_b  = (const float*)d_in[14];

  float* outp  = (float*)d_out;
  float* pred  = outp;
  float* h_new = outp + OUT_H;
  float* c_new = outp + OUT_C;

  float* ws         = (float*)d_ws;
  float* gates_part = ws + WS_GATES;
  float* score_part = ws + WS_SCORE;
  float* hatt_part  = ws + WS_HATTP;
  float* ypart      = ws + WS_YP;
  float* stats      = ws + WS_STATS;
  unsigned short* us = (unsigned short*)(ws + WS_BF);
  unsigned short* xhi  = us;
  unsigned short* xlo  = us + 65536;
  unsigned short* h0hi = us + 131072;
  unsigned short* h0lo = us + 196608;
  unsigned short* hnhi = us + 262144;
  unsigned short* hnlo = us + 327680;
  unsigned short* thi  = us + 393216;
  unsigned short* tlo  = us + 458752;
  unsigned short* Ahi  = us + 524288;
  unsigned short* Alo  = us + 589824;

  // 1) gather + bf16-split x (=emb[prev]) and h0
  prep_split<<<64, 256, 0, stream>>>(prev, emb, h0, xhi, xlo, h0hi, h0lo);
  // 2) gate partials via MFMA (2 mat x 4 kseg)
  gates_mfma<<<dim3(64, 8), 256, 0, stream>>>(
      xhi, xlo, h0hi, h0lo, W_ih, W_hh, gates_part);
  // 3) LSTM elementwise + h_new split
  k_lstm<<<256, 256, 0, stream>>>(
      gates_part, b_ih, b_hh, c0, h_new, c_new, hnhi, hnlo);
  // 4) attention score partials (16 h-chunks)
  k_scores<<<1024, 128, 0, stream>>>(h_new, enc, score_part);
  // 5) softmax + coalesced context (writes t split)
  attn_ctx<<<512, 256, 0, stream>>>(score_part, enc, thi, tlo);
  // 6) h_att partials via MFMA (2 mat x 4 kseg)
  hatt_mfma<<<dim3(16, 8), 256, 0, stream>>>(
      hnhi, hnlo, thi, tlo, W1_w, W2_w, hatt_part);
  // 7) h_att epilogue (sum + biases + tanh + split)
  hatt_ep<<<256, 256, 0, stream>>>(hatt_part, W1_b, W2_b, Ahi, Alo);
  // 8) logits via MFMA split-bf16 (K-split 2)
  gemm_big_mfma<<<dim3(500, 2), 256, 0, stream>>>(Ahi, Alo, W_w, ypart);
  // 9) log-softmax pass 1 (chunk stats)
  lse1<<<512, 256, 0, stream>>>(ypart, W_b, stats);
  // 10) log-softmax pass 2 (write pred)
  lse2<<<512, 256, 0, stream>>>(ypart, W_b, stats, pred);
}